// Round 1
// baseline (867.945 us; speedup 1.0000x reference)
//
#include <hip/hip_runtime.h>

using f16 = _Float16;
using half8  = __attribute__((ext_vector_type(8))) f16;
using half4v = __attribute__((ext_vector_type(4))) f16;
using float4v = __attribute__((ext_vector_type(4))) float;

#define DEV static __device__ __forceinline__

constexpr int N = 2048, DIM = 1024, H = 16, DH = 64, F6 = 6144;

// Stage a tile of rows (32 halves = 64 B per row) from global into LDS via
// global_load_lds width=16. NBYTES in {4096, 8192, 16384}. LDS dest must be
// contiguous in lane order: chunk (q*4+w) covers bytes [(q*4+w)*1024, +1024).
template<int NBYTES>
DEV void stage_rows(const f16* __restrict__ g, int strideHalves, f16* lds, int tid) {
  const int w = tid >> 6, l = tid & 63;
  constexpr int NISS = NBYTES >> 12;
#pragma unroll
  for (int q = 0; q < NISS; ++q) {
    const int o = ((q * 4 + w) << 10) | (l << 4);   // byte offset within tile
    const f16* gp = g + (o >> 6) * strideHalves + ((o & 63) >> 1);
    __builtin_amdgcn_global_load_lds(
        (const __attribute__((address_space(1))) unsigned int*)gp,
        (__attribute__((address_space(3))) unsigned int*)(lds + ((q * 4 + w) << 9)),
        16, 0, 0);
  }
}

// One BK=32 step: wave computes 64x64 via 4x4 grid of 16x16x32 f16 MFMAs.
// A frag: lane holds A[m=lane&15][k=(lane>>4)*8 + j]; B likewise (both [row][k], K-contig).
DEV void mfma_step(const f16* As, const f16* Bs, int wm, int wn, int l, float4v acc[4][4]) {
  const int m0 = wm + (l & 15);
  const int n0 = wn + (l & 15);
  const int k8 = (l >> 4) << 3;
  half8 af[4], bf[4];
#pragma unroll
  for (int mi = 0; mi < 4; ++mi) af[mi] = *(const half8*)(As + (m0 + mi * 16) * 32 + k8);
#pragma unroll
  for (int ni = 0; ni < 4; ++ni) bf[ni] = *(const half8*)(Bs + (n0 + ni * 16) * 32 + k8);
#pragma unroll
  for (int mi = 0; mi < 4; ++mi)
#pragma unroll
    for (int ni = 0; ni < 4; ++ni)
      acc[mi][ni] = __builtin_amdgcn_mfma_f32_16x16x32_f16(af[mi], bf[ni], acc[mi][ni], 0, 0, 0);
}

__global__ __launch_bounds__(256) void k_cast(const float* __restrict__ s, f16* __restrict__ d, int n4) {
  int i = blockIdx.x * 256 + threadIdx.x;
  if (i < n4) {
    float4 v = ((const float4*)s)[i];
    half4v h;
    h[0] = (f16)v.x; h[1] = (f16)v.y; h[2] = (f16)v.z; h[3] = (f16)v.w;
    ((half4v*)d)[i] = h;
  }
}

// qkvs = x @ w_qkv^T with scatter into per-head half buffers; qu/qc scaled by DH^-0.5.
__global__ __launch_bounds__(256) void k_qkv(const f16* __restrict__ xh, const f16* __restrict__ wh,
                                             f16* __restrict__ quh, f16* __restrict__ kuh,
                                             f16* __restrict__ vuh, f16* __restrict__ qch,
                                             f16* __restrict__ kch, f16* __restrict__ vcT) {
  __shared__ f16 As[128 * 32], Bs[128 * 32];
  const int tid = threadIdx.x, w = tid >> 6, l = tid & 63;
  const int tm = blockIdx.x * 128, tf = blockIdx.y * 128;
  const int wm = (w >> 1) * 64, wn = (w & 1) * 64;
  float4v acc[4][4] = {};
  for (int k0 = 0; k0 < DIM; k0 += 32) {
    stage_rows<8192>(xh + (size_t)tm * DIM + k0, DIM, As, tid);
    stage_rows<8192>(wh + (size_t)tf * DIM + k0, DIM, Bs, tid);
    __syncthreads();
    mfma_step(As, Bs, wm, wn, l, acc);
    __syncthreads();
  }
  const int rbase = (l >> 4) * 4, cidx = l & 15;
#pragma unroll
  for (int mi = 0; mi < 4; ++mi)
#pragma unroll
    for (int ni = 0; ni < 4; ++ni)
#pragma unroll
      for (int r = 0; r < 4; ++r) {
        const int n = tm + wm + mi * 16 + rbase + r;
        const int f = tf + wn + ni * 16 + cidx;
        float v = acc[mi][ni][r];
        const int t = f >> 10, rem = f & 1023, h = rem >> 6, d = rem & 63;
        if (t == 0 || t == 3) v *= 0.125f;
        const f16 hv = (f16)v;
        if (t == 5) {
          vcT[((size_t)h * DH + d) * N + n] = hv;  // vc transposed: [h][d][n]
        } else {
          f16* dst = (t == 0) ? quh : (t == 1) ? kuh : (t == 2) ? vuh : (t == 3) ? qch : kch;
          dst[((size_t)h * N + n) * DH + d] = hv;
        }
      }
}

// term1 = tril(qc.vu^T) (tj<=ti tiles) and sig = triu1(sigmoid(qu.ku^T)) (tj>=ti tiles).
__global__ __launch_bounds__(256) void k_t1sig(const f16* __restrict__ qch, const f16* __restrict__ quh,
                                               const f16* __restrict__ vuh, const f16* __restrict__ kuh,
                                               f16* __restrict__ term1, f16* __restrict__ sigb, int h0) {
  const int tj = blockIdx.x, ti = blockIdx.y, hl = blockIdx.z, h = h0 + hl;
  __shared__ f16 As[128 * 32], Bs[128 * 32];
  const int tid = threadIdx.x, w = tid >> 6, l = tid & 63;
  const int wm = (w >> 1) * 64, wn = (w & 1) * 64;
  const size_t ho = (size_t)h * N * DH;
  const int rbase = (l >> 4) * 4, cidx = l & 15;
  if (tj <= ti) {
    float4v acc[4][4] = {};
#pragma unroll
    for (int k0 = 0; k0 < DH; k0 += 32) {
      stage_rows<8192>(qch + ho + (size_t)(ti * 128) * DH + k0, DH, As, tid);
      stage_rows<8192>(vuh + ho + (size_t)(tj * 128) * DH + k0, DH, Bs, tid);
      __syncthreads();
      mfma_step(As, Bs, wm, wn, l, acc);
      __syncthreads();
    }
#pragma unroll
    for (int mi = 0; mi < 4; ++mi)
#pragma unroll
      for (int ni = 0; ni < 4; ++ni)
#pragma unroll
        for (int r = 0; r < 4; ++r) {
          const int i = ti * 128 + wm + mi * 16 + rbase + r;
          const int j = tj * 128 + wn + ni * 16 + cidx;
          term1[(size_t)hl * N * N + (size_t)i * N + j] = (j <= i) ? (f16)acc[mi][ni][r] : (f16)0.f;
        }
  }
  if (tj >= ti) {
    float4v acc[4][4] = {};
#pragma unroll
    for (int k0 = 0; k0 < DH; k0 += 32) {
      stage_rows<8192>(quh + ho + (size_t)(ti * 128) * DH + k0, DH, As, tid);
      stage_rows<8192>(kuh + ho + (size_t)(tj * 128) * DH + k0, DH, Bs, tid);
      __syncthreads();
      mfma_step(As, Bs, wm, wn, l, acc);
      __syncthreads();
    }
#pragma unroll
    for (int mi = 0; mi < 4; ++mi)
#pragma unroll
      for (int ni = 0; ni < 4; ++ni)
#pragma unroll
        for (int r = 0; r < 4; ++r) {
          const int i = ti * 128 + wm + mi * 16 + rbase + r;
          const int j = tj * 128 + wn + ni * 16 + cidx;
          float x = acc[mi][ni][r];
          float sg = (j > i) ? 1.f / (1.f + __expf(-x)) : 0.f;
          sigb[(size_t)hl * N * N + (size_t)i * N + j] = (f16)sg;
        }
  }
}

// scores = qc.kc^T - silu(term1 @ sig^T), lower-triangle tiles only, fp32 out.
// K-loop over j clamped to [tk*128, (ti+1)*128) — triangular masking of term1/sig
// makes the clamp exact. silu fused via MFMA C-operand: acc := -silu(Su); acc += Sc.
__global__ __launch_bounds__(256) void k_su(const f16* __restrict__ term1, const f16* __restrict__ sigb,
                                            const f16* __restrict__ qch, const f16* __restrict__ kch,
                                            float* __restrict__ scob, int h0) {
  const int tk = blockIdx.x, ti = blockIdx.y, hl = blockIdx.z;
  if (tk > ti) return;
  __shared__ f16 As[128 * 32], Bs[128 * 32];
  const int tid = threadIdx.x, w = tid >> 6, l = tid & 63;
  const int wm = (w >> 1) * 64, wn = (w & 1) * 64;
  float4v acc[4][4] = {};
  const f16* Ab = term1 + (size_t)hl * N * N + (size_t)(ti * 128) * N;
  const f16* Bb = sigb + (size_t)hl * N * N + (size_t)(tk * 128) * N;
  const int jhi = (ti + 1) * 128;
  for (int j0 = tk * 128; j0 < jhi; j0 += 32) {
    stage_rows<8192>(Ab + j0, N, As, tid);
    stage_rows<8192>(Bb + j0, N, Bs, tid);
    __syncthreads();
    mfma_step(As, Bs, wm, wn, l, acc);
    __syncthreads();
  }
#pragma unroll
  for (int mi = 0; mi < 4; ++mi)
#pragma unroll
    for (int ni = 0; ni < 4; ++ni)
#pragma unroll
      for (int r = 0; r < 4; ++r) {
        const float x = acc[mi][ni][r];
        acc[mi][ni][r] = -(x / (1.f + __expf(-x)));  // -silu(Su)
      }
  const int h = h0 + hl;
  const size_t ho = (size_t)h * N * DH;
#pragma unroll
  for (int k0 = 0; k0 < DH; k0 += 32) {
    stage_rows<8192>(qch + ho + (size_t)(ti * 128) * DH + k0, DH, As, tid);
    stage_rows<8192>(kch + ho + (size_t)(tk * 128) * DH + k0, DH, Bs, tid);
    __syncthreads();
    mfma_step(As, Bs, wm, wn, l, acc);  // acc = Sc - silu(Su)
    __syncthreads();
  }
  const int rbase = (l >> 4) * 4, cidx = l & 15;
#pragma unroll
  for (int mi = 0; mi < 4; ++mi)
#pragma unroll
    for (int ni = 0; ni < 4; ++ni)
#pragma unroll
      for (int r = 0; r < 4; ++r) {
        const int i = ti * 128 + wm + mi * 16 + rbase + r;
        const int k = tk * 128 + wn + ni * 16 + cidx;
        if (k <= i) scob[(size_t)hl * N * N + (size_t)i * N + k] = acc[mi][ni][r];
      }
}

// Row softmax over k<=i; writes attn (half) zero-padded to the next 256 boundary
// so k_av's tile-granular K-loop reads no poison.
__global__ __launch_bounds__(256) void k_softmax(const float* __restrict__ scob, f16* __restrict__ attn) {
  const int tid = threadIdx.x, l = tid & 63;
  const int row = blockIdx.x * 4 + (tid >> 6);
  const int hl = row >> 11, i = row & 2047;
  const float* src = scob + (size_t)hl * N * N + (size_t)i * N;
  f16* dst = attn + (size_t)hl * N * N + (size_t)i * N;
  float v[32];
  float mx = -1e30f;
#pragma unroll
  for (int c = 0; c < 32; ++c) {
    const int k = c * 64 + l;
    const float val = (k <= i) ? src[k] : -1e30f;
    v[c] = val;
    mx = fmaxf(mx, val);
  }
#pragma unroll
  for (int m = 1; m < 64; m <<= 1) mx = fmaxf(mx, __shfl_xor(mx, m, 64));
  float s = 0.f;
#pragma unroll
  for (int c = 0; c < 32; ++c) {
    const float e = __expf(v[c] - mx);
    v[c] = e;
    s += e;
  }
#pragma unroll
  for (int m = 1; m < 64; m <<= 1) s += __shfl_xor(s, m, 64);
  const float inv = 1.f / s;
  const int kw = ((i >> 8) + 1) << 8;
#pragma unroll
  for (int c = 0; c < 32; ++c) {
    const int k = c * 64 + l;
    if (k < kw) dst[k] = (f16)(v[c] * inv);
  }
}

// O[:, h*64:(h+1)*64] = attn @ vc ; 256x64 tile, K clamped to (mt+1)*256 (causal).
__global__ __launch_bounds__(256) void k_av(const f16* __restrict__ attn, const f16* __restrict__ vcT,
                                            f16* __restrict__ O, int h0) {
  const int mt = blockIdx.x, hl = blockIdx.y, h = h0 + hl;
  __shared__ f16 As[256 * 32], Bs[64 * 32];
  const int tid = threadIdx.x, w = tid >> 6, l = tid & 63;
  const int wm = w * 64;
  float4v acc[4][4] = {};
  const f16* Ab = attn + (size_t)hl * N * N + (size_t)(mt * 256) * N;
  const f16* Bb = vcT + (size_t)h * DH * N;
  const int jhi = (mt + 1) * 256;
  for (int j0 = 0; j0 < jhi; j0 += 32) {
    stage_rows<16384>(Ab + j0, N, As, tid);
    stage_rows<4096>(Bb + j0, N, Bs, tid);
    __syncthreads();
    mfma_step(As + wm * 32, Bs, 0, 0, l, acc);
    __syncthreads();
  }
  const int rbase = (l >> 4) * 4, cidx = l & 15;
#pragma unroll
  for (int mi = 0; mi < 4; ++mi)
#pragma unroll
    for (int ni = 0; ni < 4; ++ni)
#pragma unroll
      for (int r = 0; r < 4; ++r) {
        const int i = mt * 256 + wm + mi * 16 + rbase + r;
        const int d = ni * 16 + cidx;
        O[(size_t)i * (H * DH) + h * DH + d] = (f16)acc[mi][ni][r];
      }
}

// out = O @ w_out^T, fp32 result.
__global__ __launch_bounds__(256) void k_out(const f16* __restrict__ Oh, const f16* __restrict__ wo,
                                             float* __restrict__ out) {
  __shared__ f16 As[128 * 32], Bs[128 * 32];
  const int tid = threadIdx.x, w = tid >> 6, l = tid & 63;
  const int tm = blockIdx.x * 128, tn = blockIdx.y * 128;
  const int wm = (w >> 1) * 64, wn = (w & 1) * 64;
  float4v acc[4][4] = {};
  for (int k0 = 0; k0 < DIM; k0 += 32) {
    stage_rows<8192>(Oh + (size_t)tm * DIM + k0, DIM, As, tid);
    stage_rows<8192>(wo + (size_t)tn * DIM + k0, DIM, Bs, tid);
    __syncthreads();
    mfma_step(As, Bs, wm, wn, l, acc);
    __syncthreads();
  }
  const int rbase = (l >> 4) * 4, cidx = l & 15;
#pragma unroll
  for (int mi = 0; mi < 4; ++mi)
#pragma unroll
    for (int ni = 0; ni < 4; ++ni)
#pragma unroll
      for (int r = 0; r < 4; ++r) {
        const int n = tm + wm + mi * 16 + rbase + r;
        const int dmo = tn + wn + ni * 16 + cidx;
        out[(size_t)n * DIM + dmo] = acc[mi][ni][r];
      }
}

extern "C" void kernel_launch(void* const* d_in, const int* in_sizes, int n_in,
                              void* d_out, int out_size, void* d_ws, size_t ws_size,
                              hipStream_t stream) {
  const float* x = (const float*)d_in[0];
  const float* wqkv = (const float*)d_in[1];
  const float* wout = (const float*)d_in[2];
  float* out = (float*)d_out;
  char* ws = (char*)d_ws;

  size_t off = 0;
  auto alloc = [&](size_t b) { size_t o = off; off += (b + 255) & ~(size_t)255; return o; };
  f16* xh  = (f16*)(ws + alloc((size_t)N * DIM * 2));
  f16* wqh = (f16*)(ws + alloc((size_t)F6 * DIM * 2));
  f16* woh = (f16*)(ws + alloc((size_t)DIM * H * DH * 2));
  f16* quh = (f16*)(ws + alloc((size_t)H * N * DH * 2));
  f16* kuh = (f16*)(ws + alloc((size_t)H * N * DH * 2));
  f16* vuh = (f16*)(ws + alloc((size_t)H * N * DH * 2));
  f16* qch = (f16*)(ws + alloc((size_t)H * N * DH * 2));
  f16* kch = (f16*)(ws + alloc((size_t)H * N * DH * 2));
  f16* vcT = (f16*)(ws + alloc((size_t)H * DH * N * 2));
  f16* Oh  = (f16*)(ws + alloc((size_t)N * H * DH * 2));
  const size_t persist = off;

  // choose largest head-group G whose [G,N,N] term1/sig(half) + scores(fp32) fit ws
  int G = 16;
  while (G > 1 && persist + (size_t)G * N * N * (2 + 2 + 4) + 1024 > ws_size) G >>= 1;
  f16* term1  = (f16*)(ws + alloc((size_t)G * N * N * 2));   // reused as attn after softmax
  f16* sigb   = (f16*)(ws + alloc((size_t)G * N * N * 2));
  float* scob = (float*)(ws + alloc((size_t)G * N * N * 4));

  k_cast<<<(N * DIM / 4 + 255) / 256, 256, 0, stream>>>(x, xh, N * DIM / 4);
  k_cast<<<(F6 * DIM / 4 + 255) / 256, 256, 0, stream>>>(wqkv, wqh, F6 * DIM / 4);
  k_cast<<<(DIM * H * DH / 4 + 255) / 256, 256, 0, stream>>>(wout, woh, DIM * H * DH / 4);

  k_qkv<<<dim3(N / 128, F6 / 128), 256, 0, stream>>>(xh, wqh, quh, kuh, vuh, qch, kch, vcT);

  for (int h0 = 0; h0 < H; h0 += G) {
    k_t1sig<<<dim3(16, 16, G), 256, 0, stream>>>(qch, quh, vuh, kuh, term1, sigb, h0);
    k_su<<<dim3(16, 16, G), 256, 0, stream>>>(term1, sigb, qch, kch, scob, h0);
    k_softmax<<<G * 512, 256, 0, stream>>>(scob, term1);
    k_av<<<dim3(8, G), 256, 0, stream>>>(term1, vcT, Oh, h0);
  }

  k_out<<<dim3(16, 8), 256, 0, stream>>>(Oh, woh, out);
}

// Round 2
// 562.583 us; speedup vs baseline: 1.5428x; 1.5428x over previous
//
#include <hip/hip_runtime.h>

using f16 = _Float16;
using half8  = __attribute__((ext_vector_type(8))) f16;
using half4v = __attribute__((ext_vector_type(4))) f16;
using float4v = __attribute__((ext_vector_type(4))) float;

#define DEV static __device__ __forceinline__

constexpr int N = 2048, DIM = 1024, H = 16, DH = 64, F6 = 6144;
constexpr int LDSH = 136;  // f16 epilogue row stride (halves) -> 2-way max on b16 writes
constexpr int LDSF = 132;  // f32 epilogue row stride (floats) -> 2-way max on b32 writes

// Stage ROWS x 64-half tile. 16B chunks XOR-swizzled within each row's 8 chunks:
// LDS chunk (m*8+c) holds global chunk (m, c^(m&7)). Keeps global_load_lds's
// lane-linear LDS dest AND makes frag ds_read_b128 conflict-free (2-way max).
template<int ROWS>
DEV void stage64(const f16* __restrict__ g, int strideHalves, f16* lds, int tid) {
#pragma unroll
  for (int q = 0; q < (ROWS * 8) / 256; ++q) {
    const int chunk = q * 256 + tid;
    const int m = chunk >> 3, c = (chunk & 7) ^ (m & 7);
    const f16* gp = g + (size_t)m * strideHalves + c * 8;
    __builtin_amdgcn_global_load_lds(
        (const __attribute__((address_space(1))) unsigned int*)gp,
        (__attribute__((address_space(3))) unsigned int*)(lds + chunk * 8), 16, 0, 0);
  }
}

DEV half8 rdfrag(const f16* T, int m, int ks, int q) {
  const int c = (ks * 4 + q) ^ (m & 7);
  return *(const half8*)(T + m * 64 + c * 8);
}

// One BK=64 step: 2 sub-steps of 16x16x32 f16 MFMA; wave computes 64x64.
DEV void gemm64(const f16* As, const f16* Bs, int wm, int wn, int l, float4v acc[4][4]) {
  const int q = l >> 4, mm = l & 15;
#pragma unroll
  for (int ks = 0; ks < 2; ++ks) {
    half8 af[4], bf[4];
#pragma unroll
    for (int mi = 0; mi < 4; ++mi) af[mi] = rdfrag(As, wm + mm + mi * 16, ks, q);
#pragma unroll
    for (int ni = 0; ni < 4; ++ni) bf[ni] = rdfrag(Bs, wn + mm + ni * 16, ks, q);
#pragma unroll
    for (int mi = 0; mi < 4; ++mi)
#pragma unroll
      for (int ni = 0; ni < 4; ++ni)
        acc[mi][ni] = __builtin_amdgcn_mfma_f32_16x16x32_f16(af[mi], bf[ni], acc[mi][ni], 0, 0, 0);
  }
}

// Read back a 128x128 f16 tile from lds (stride LDSH) -> coalesced b128 stores.
DEV void flush_f16(const f16* lds, f16* __restrict__ g, int strideHalves, int tid) {
  __syncthreads();
#pragma unroll
  for (int q = 0; q < 8; ++q) {
    const int idx = q * 256 + tid, row = idx >> 4, c = idx & 15;
    *(half8*)(g + (size_t)row * strideHalves + c * 8) = *(const half8*)(lds + row * LDSH + c * 8);
  }
  __syncthreads();
}

// p in [0,136) -> (ti,tk), tk<=ti, ordered longest-K-first (ti-tk descending).
DEV void decode_pair(int p, int& ti, int& tk) {
  int t = (int)((sqrtf(8.f * p + 1.f) - 1.f) * 0.5f);
  while (t * (t + 1) / 2 > p) --t;
  while ((t + 1) * (t + 2) / 2 <= p) ++t;
  const int i2 = p - t * (t + 1) / 2;
  ti = (15 - t) + i2;
  tk = i2;
}

__global__ __launch_bounds__(256) void k_cast(const float* __restrict__ s, f16* __restrict__ d, int n4) {
  int i = blockIdx.x * 256 + threadIdx.x;
  if (i < n4) {
    float4 v = ((const float4*)s)[i];
    half4v h;
    h[0] = (f16)v.x; h[1] = (f16)v.y; h[2] = (f16)v.z; h[3] = (f16)v.w;
    ((half4v*)d)[i] = h;
  }
}

// qkvs = x @ w_qkv^T; per-head scatter. Each block's 128-wide f-window lies in ONE
// of the 6 qkv slots (t), so the epilogue branch is block-uniform.
__global__ __launch_bounds__(256) void k_qkv(const f16* __restrict__ xh, const f16* __restrict__ wh,
                                             f16* __restrict__ quh, f16* __restrict__ kuh,
                                             f16* __restrict__ vuh, f16* __restrict__ qch,
                                             f16* __restrict__ kch, f16* __restrict__ vcT) {
  __shared__ __align__(16) f16 lds[128 * LDSH];
  f16* As = lds; f16* Bs = lds + 128 * 64;
  const int tid = threadIdx.x, w = tid >> 6, l = tid & 63;
  const int tm = blockIdx.x * 128, tf = blockIdx.y * 128;
  const int wm = (w >> 1) * 64, wn = (w & 1) * 64;
  float4v acc[4][4] = {};
  for (int k0 = 0; k0 < DIM; k0 += 64) {
    stage64<128>(xh + (size_t)tm * DIM + k0, DIM, As, tid);
    stage64<128>(wh + (size_t)tf * DIM + k0, DIM, Bs, tid);
    __syncthreads();
    gemm64(As, Bs, wm, wn, l, acc);
    __syncthreads();
  }
  const int rbase = (l >> 4) * 4, cidx = l & 15;
  const int t = tf >> 10;
  const float sc = (t == 0 || t == 3) ? 0.125f : 1.f;
  if (t == 5) {  // vc transposed [h][d][n]: lane's 4 r-values are n-consecutive -> b64
#pragma unroll
    for (int mi = 0; mi < 4; ++mi)
#pragma unroll
      for (int ni = 0; ni < 4; ++ni) {
        const int f = tf + wn + ni * 16 + cidx;
        const int h = (f & 1023) >> 6, d = f & 63;
        half4v p;
#pragma unroll
        for (int r = 0; r < 4; ++r) p[r] = (f16)acc[mi][ni][r];
        *(half4v*)(vcT + ((size_t)h * DH + d) * N + (tm + wm + mi * 16 + rbase)) = p;
      }
  } else {
#pragma unroll
    for (int mi = 0; mi < 4; ++mi)
#pragma unroll
      for (int ni = 0; ni < 4; ++ni)
#pragma unroll
        for (int r = 0; r < 4; ++r)
          lds[(wm + mi * 16 + rbase + r) * LDSH + wn + ni * 16 + cidx] = (f16)(acc[mi][ni][r] * sc);
    __syncthreads();
    f16* dst = (t == 0) ? quh : (t == 1) ? kuh : (t == 2) ? vuh : (t == 3) ? qch : kch;
    const int hb = (tf & 1023) >> 6;
#pragma unroll
    for (int q = 0; q < 8; ++q) {
      const int idx = q * 256 + tid, row = idx >> 4, c = idx & 15;
      const int h = hb + (c >> 3), d0 = (c & 7) * 8, n = tm + row;
      *(half8*)(dst + ((size_t)h * N + n) * DH + d0) = *(const half8*)(lds + row * LDSH + c * 8);
    }
  }
}

// Per pair (a<=b): term1 tile (ti=b,tj=a) = tril(qc.vu^T) and sig tile (ti=a,tj=b)
// = triu1(sigmoid(qu.ku^T)). Uniform 2 GEMMs (K=64) per block, vectorized stores.
__global__ __launch_bounds__(256) void k_t1sig(const f16* __restrict__ qch, const f16* __restrict__ quh,
                                               const f16* __restrict__ vuh, const f16* __restrict__ kuh,
                                               f16* __restrict__ term1, f16* __restrict__ sigb, int h0) {
  __shared__ __align__(16) f16 lds[128 * LDSH];
  f16* As = lds; f16* Bs = lds + 128 * 64;
  int b, a;
  decode_pair(blockIdx.x, b, a);
  const int hl = blockIdx.y, h = h0 + hl;
  const int tid = threadIdx.x, w = tid >> 6, l = tid & 63;
  const int wm = (w >> 1) * 64, wn = (w & 1) * 64;
  const int rbase = (l >> 4) * 4, cidx = l & 15;
  const size_t ho = (size_t)h * N * DH;

  {  // term1
    float4v acc[4][4] = {};
    stage64<128>(qch + ho + (size_t)(b * 128) * DH, DH, As, tid);
    stage64<128>(vuh + ho + (size_t)(a * 128) * DH, DH, Bs, tid);
    __syncthreads();
    gemm64(As, Bs, wm, wn, l, acc);
    __syncthreads();
#pragma unroll
    for (int mi = 0; mi < 4; ++mi)
#pragma unroll
      for (int ni = 0; ni < 4; ++ni)
#pragma unroll
        for (int r = 0; r < 4; ++r) {
          const int i = b * 128 + wm + mi * 16 + rbase + r;
          const int j = a * 128 + wn + ni * 16 + cidx;
          lds[(wm + mi * 16 + rbase + r) * LDSH + wn + ni * 16 + cidx] = (j <= i) ? (f16)acc[mi][ni][r] : (f16)0.f;
        }
    flush_f16(lds, term1 + (size_t)hl * N * N + (size_t)(b * 128) * N + a * 128, N, tid);
  }
  {  // sig
    float4v acc[4][4] = {};
    stage64<128>(quh + ho + (size_t)(a * 128) * DH, DH, As, tid);
    stage64<128>(kuh + ho + (size_t)(b * 128) * DH, DH, Bs, tid);
    __syncthreads();
    gemm64(As, Bs, wm, wn, l, acc);
    __syncthreads();
#pragma unroll
    for (int mi = 0; mi < 4; ++mi)
#pragma unroll
      for (int ni = 0; ni < 4; ++ni)
#pragma unroll
        for (int r = 0; r < 4; ++r) {
          const int i = a * 128 + wm + mi * 16 + rbase + r;
          const int j = b * 128 + wn + ni * 16 + cidx;
          const float x = acc[mi][ni][r];
          lds[(wm + mi * 16 + rbase + r) * LDSH + wn + ni * 16 + cidx] =
              (j > i) ? (f16)(1.f / (1.f + __expf(-x))) : (f16)0.f;
        }
    flush_f16(lds, sigb + (size_t)hl * N * N + (size_t)(a * 128) * N + b * 128, N, tid);
  }
}

// scores = qc.kc^T - silu(term1 @ sig^T); compact triangular grid, longest-K first,
// BK=64, silu fused via MFMA C-operand; fp32 epilogue vectorized via LDS (2 halves).
__global__ __launch_bounds__(256) void k_su(const f16* __restrict__ term1, const f16* __restrict__ sigb,
                                            const f16* __restrict__ qch, const f16* __restrict__ kch,
                                            float* __restrict__ scob, int h0) {
  __shared__ __align__(16) f16 lds[128 * LDSH];
  f16* As = lds; f16* Bs = lds + 128 * 64;
  int ti, tk;
  decode_pair(blockIdx.x, ti, tk);
  const int hl = blockIdx.y;
  const int tid = threadIdx.x, w = tid >> 6, l = tid & 63;
  const int wm = (w >> 1) * 64, wn = (w & 1) * 64;
  float4v acc[4][4] = {};
  const f16* Ab = term1 + (size_t)hl * N * N + (size_t)(ti * 128) * N;
  const f16* Bb = sigb + (size_t)hl * N * N + (size_t)(tk * 128) * N;
  const int jhi = (ti + 1) * 128;
  for (int j0 = tk * 128; j0 < jhi; j0 += 64) {
    stage64<128>(Ab + j0, N, As, tid);
    stage64<128>(Bb + j0, N, Bs, tid);
    __syncthreads();
    gemm64(As, Bs, wm, wn, l, acc);
    __syncthreads();
  }
#pragma unroll
  for (int mi = 0; mi < 4; ++mi)
#pragma unroll
    for (int ni = 0; ni < 4; ++ni)
#pragma unroll
      for (int r = 0; r < 4; ++r) {
        const float x = acc[mi][ni][r];
        acc[mi][ni][r] = -(x / (1.f + __expf(-x)));  // -silu(Su)
      }
  const size_t ho = (size_t)(h0 + hl) * N * DH;
  stage64<128>(qch + ho + (size_t)(ti * 128) * DH, DH, As, tid);
  stage64<128>(kch + ho + (size_t)(tk * 128) * DH, DH, Bs, tid);
  __syncthreads();
  gemm64(As, Bs, wm, wn, l, acc);  // acc = Sc - silu(Su)
  __syncthreads();

  float* ldsf = (float*)lds;
  float* gs = scob + (size_t)hl * N * N + (size_t)(ti * 128) * N + tk * 128;
  const int rbase = (l >> 4) * 4, cidx = l & 15;
#pragma unroll
  for (int hf = 0; hf < 2; ++hf) {
    if ((wm >> 6) == hf) {
#pragma unroll
      for (int mi = 0; mi < 4; ++mi)
#pragma unroll
        for (int ni = 0; ni < 4; ++ni)
#pragma unroll
          for (int r = 0; r < 4; ++r)
            ldsf[(mi * 16 + rbase + r) * LDSF + wn + ni * 16 + cidx] = acc[mi][ni][r];
    }
    __syncthreads();
#pragma unroll
    for (int q = 0; q < 8; ++q) {
      const int idx = q * 256 + tid, row = idx >> 5, c = idx & 31;
      *(float4v*)(gs + (size_t)(hf * 64 + row) * N + c * 4) = *(const float4v*)(ldsf + row * LDSF + c * 4);
    }
    __syncthreads();
  }
}

// Row softmax over k<=i, float4 reads + packed b64 f16 writes; zero-pads to the
// next 256 boundary so k_av's tile-granular K-loop reads no poison.
__global__ __launch_bounds__(256) void k_softmax(const float* __restrict__ scob, f16* __restrict__ attn) {
  const int tid = threadIdx.x, l = tid & 63;
  const int row = blockIdx.x * 4 + (tid >> 6);
  const int hl = row >> 11, i = row & 2047;
  const float* src = scob + (size_t)hl * N * N + (size_t)i * N;
  f16* dst = attn + (size_t)hl * N * N + (size_t)i * N;
  float4v v[8];
  float mx = -1e30f;
#pragma unroll
  for (int c = 0; c < 8; ++c) {
    const int idx = c * 64 + l;
    float4v t4 = ((const float4v*)src)[idx];
#pragma unroll
    for (int e = 0; e < 4; ++e) {
      const float val = (idx * 4 + e <= i) ? t4[e] : -1e30f;
      v[c][e] = val;
      mx = fmaxf(mx, val);
    }
  }
#pragma unroll
  for (int m = 1; m < 64; m <<= 1) mx = fmaxf(mx, __shfl_xor(mx, m, 64));
  float s = 0.f;
#pragma unroll
  for (int c = 0; c < 8; ++c)
#pragma unroll
    for (int e = 0; e < 4; ++e) {
      const float ex = __expf(v[c][e] - mx);
      v[c][e] = ex;
      s += ex;
    }
#pragma unroll
  for (int m = 1; m < 64; m <<= 1) s += __shfl_xor(s, m, 64);
  const float inv = 1.f / s;
  const int kw4 = (((i >> 8) + 1) << 8) >> 2;
#pragma unroll
  for (int c = 0; c < 8; ++c) {
    const int idx = c * 64 + l;
    if (idx < kw4) {
      half4v o;
#pragma unroll
      for (int e = 0; e < 4; ++e) o[e] = (f16)(v[c][e] * inv);
      ((half4v*)dst)[idx] = o;
    }
  }
}

// O[:, h*64:(h+1)*64] = attn @ vc; 64x64 tiles, longest-K-first, BK=64.
__global__ __launch_bounds__(256) void k_av(const f16* __restrict__ attn, const f16* __restrict__ vcT,
                                            f16* __restrict__ O, int h0) {
  __shared__ __align__(16) f16 As[64 * 64], Bs[64 * 64];
  const int mt = 31 - blockIdx.x, hl = blockIdx.y, h = h0 + hl;
  const int tid = threadIdx.x, w = tid >> 6, l = tid & 63;
  const int q = l >> 4, mm = l & 15;
  float4v acc[4] = {};
  const f16* Ab = attn + (size_t)hl * N * N + (size_t)(mt * 64) * N;
  const f16* Bb = vcT + (size_t)h * DH * N;
  const int jhi = (mt + 1) * 64;
  for (int j0 = 0; j0 < jhi; j0 += 64) {
    stage64<64>(Ab + j0, N, As, tid);
    stage64<64>(Bb + j0, N, Bs, tid);
    __syncthreads();
#pragma unroll
    for (int ks = 0; ks < 2; ++ks) {
      half8 bf = rdfrag(Bs, w * 16 + mm, ks, q);
#pragma unroll
      for (int mi = 0; mi < 4; ++mi) {
        half8 af = rdfrag(As, mm + mi * 16, ks, q);
        acc[mi] = __builtin_amdgcn_mfma_f32_16x16x32_f16(af, bf, acc[mi], 0, 0, 0);
      }
    }
    __syncthreads();
  }
  const int rbase = (l >> 4) * 4, cidx = l & 15;
#pragma unroll
  for (int mi = 0; mi < 4; ++mi)
#pragma unroll
    for (int r = 0; r < 4; ++r) {
      const int i = mt * 64 + mi * 16 + rbase + r;
      O[(size_t)i * (H * DH) + h * DH + w * 16 + cidx] = (f16)acc[mi][r];
    }
}

// out = O @ w_out^T, fp32 result.
__global__ __launch_bounds__(256) void k_out(const f16* __restrict__ Oh, const f16* __restrict__ wo,
                                             float* __restrict__ out) {
  __shared__ __align__(16) f16 lds[128 * LDSH];
  f16* As = lds; f16* Bs = lds + 128 * 64;
  const int tid = threadIdx.x, w = tid >> 6, l = tid & 63;
  const int tm = blockIdx.x * 128, tn = blockIdx.y * 128;
  const int wm = (w >> 1) * 64, wn = (w & 1) * 64;
  float4v acc[4][4] = {};
  for (int k0 = 0; k0 < DIM; k0 += 64) {
    stage64<128>(Oh + (size_t)tm * DIM + k0, DIM, As, tid);
    stage64<128>(wo + (size_t)tn * DIM + k0, DIM, Bs, tid);
    __syncthreads();
    gemm64(As, Bs, wm, wn, l, acc);
    __syncthreads();
  }
  const int rbase = (l >> 4) * 4, cidx = l & 15;
#pragma unroll
  for (int mi = 0; mi < 4; ++mi)
#pragma unroll
    for (int ni = 0; ni < 4; ++ni)
#pragma unroll
      for (int r = 0; r < 4; ++r) {
        const int n = tm + wm + mi * 16 + rbase + r;
        const int dmo = tn + wn + ni * 16 + cidx;
        out[(size_t)n * DIM + dmo] = acc[mi][ni][r];
      }
}

extern "C" void kernel_launch(void* const* d_in, const int* in_sizes, int n_in,
                              void* d_out, int out_size, void* d_ws, size_t ws_size,
                              hipStream_t stream) {
  const float* x = (const float*)d_in[0];
  const float* wqkv = (const float*)d_in[1];
  const float* wout = (const float*)d_in[2];
  float* out = (float*)d_out;
  char* ws = (char*)d_ws;

  size_t off = 0;
  auto alloc = [&](size_t b) { size_t o = off; off += (b + 255) & ~(size_t)255; return o; };
  f16* xh  = (f16*)(ws + alloc((size_t)N * DIM * 2));
  f16* wqh = (f16*)(ws + alloc((size_t)F6 * DIM * 2));
  f16* woh = (f16*)(ws + alloc((size_t)DIM * H * DH * 2));
  f16* quh = (f16*)(ws + alloc((size_t)H * N * DH * 2));
  f16* kuh = (f16*)(ws + alloc((size_t)H * N * DH * 2));
  f16* vuh = (f16*)(ws + alloc((size_t)H * N * DH * 2));
  f16* qch = (f16*)(ws + alloc((size_t)H * N * DH * 2));
  f16* kch = (f16*)(ws + alloc((size_t)H * N * DH * 2));
  f16* vcT = (f16*)(ws + alloc((size_t)H * DH * N * 2));
  f16* Oh  = (f16*)(ws + alloc((size_t)N * H * DH * 2));
  const size_t persist = off;

  int G = 16;
  while (G > 1 && persist + (size_t)G * N * N * (2 + 2 + 4) + 1024 > ws_size) G >>= 1;
  f16* term1  = (f16*)(ws + alloc((size_t)G * N * N * 2));   // reused as attn after softmax
  f16* sigb   = (f16*)(ws + alloc((size_t)G * N * N * 2));
  float* scob = (float*)(ws + alloc((size_t)G * N * N * 4));

  k_cast<<<(N * DIM / 4 + 255) / 256, 256, 0, stream>>>(x, xh, N * DIM / 4);
  k_cast<<<(F6 * DIM / 4 + 255) / 256, 256, 0, stream>>>(wqkv, wqh, F6 * DIM / 4);
  k_cast<<<(DIM * H * DH / 4 + 255) / 256, 256, 0, stream>>>(wout, woh, DIM * H * DH / 4);

  k_qkv<<<dim3(N / 128, F6 / 128), 256, 0, stream>>>(xh, wqh, quh, kuh, vuh, qch, kch, vcT);

  for (int h0 = 0; h0 < H; h0 += G) {
    k_t1sig<<<dim3(136, G), 256, 0, stream>>>(qch, quh, vuh, kuh, term1, sigb, h0);
    k_su<<<dim3(136, G), 256, 0, stream>>>(term1, sigb, qch, kch, scob, h0);
    k_softmax<<<G * 512, 256, 0, stream>>>(scob, term1);
    k_av<<<dim3(32, G), 256, 0, stream>>>(term1, vcT, Oh, h0);
  }

  k_out<<<dim3(16, 8), 256, 0, stream>>>(Oh, woh, out);
}

// Round 3
// 447.073 us; speedup vs baseline: 1.9414x; 1.2584x over previous
//
#include <hip/hip_runtime.h>

using f16 = _Float16;
using half8  = __attribute__((ext_vector_type(8))) f16;
using half4v = __attribute__((ext_vector_type(4))) f16;
using float4v = __attribute__((ext_vector_type(4))) float;

#define DEV static __device__ __forceinline__

constexpr int N = 2048, DIM = 1024, H = 16, DH = 64, F6 = 6144;
constexpr int LDSH = 136;  // f16 epilogue row stride (halves)

// Stage ROWS x 64-half tile with THREADS threads. 16B chunks XOR-swizzled within
// each row's 8 chunks: LDS chunk (m*8+c) holds global chunk (m, c^(m&7)). Keeps
// global_load_lds's lane-linear LDS dest AND makes frag ds_read_b128 conflict-free.
template<int ROWS, int THREADS>
DEV void stage64(const f16* __restrict__ g, int strideHalves, f16* lds, int tid) {
#pragma unroll
  for (int q = 0; q < (ROWS * 8) / THREADS; ++q) {
    const int chunk = q * THREADS + tid;
    const int m = chunk >> 3, c = (chunk & 7) ^ (m & 7);
    const f16* gp = g + (size_t)m * strideHalves + c * 8;
    __builtin_amdgcn_global_load_lds(
        (const __attribute__((address_space(1))) unsigned int*)gp,
        (__attribute__((address_space(3))) unsigned int*)(lds + chunk * 8), 16, 0, 0);
  }
}

DEV half8 rdfrag(const f16* T, int m, int ks, int q) {
  const int c = (ks * 4 + q) ^ (m & 7);
  return *(const half8*)(T + m * 64 + c * 8);
}

// One BK=64 step: 2 sub-steps of 16x16x32 f16 MFMA; wave computes 64x64.
DEV void gemm64(const f16* As, const f16* Bs, int wm, int wn, int l, float4v acc[4][4]) {
  const int q = l >> 4, mm = l & 15;
#pragma unroll
  for (int ks = 0; ks < 2; ++ks) {
    half8 af[4], bf[4];
#pragma unroll
    for (int mi = 0; mi < 4; ++mi) af[mi] = rdfrag(As, wm + mm + mi * 16, ks, q);
#pragma unroll
    for (int ni = 0; ni < 4; ++ni) bf[ni] = rdfrag(Bs, wn + mm + ni * 16, ks, q);
#pragma unroll
    for (int mi = 0; mi < 4; ++mi)
#pragma unroll
      for (int ni = 0; ni < 4; ++ni)
        acc[mi][ni] = __builtin_amdgcn_mfma_f32_16x16x32_f16(af[mi], bf[ni], acc[mi][ni], 0, 0, 0);
  }
}

// Read back a ROWSx128 f16 tile from lds (stride LDSH) -> coalesced b128 stores.
template<int ROWS, int THREADS>
DEV void flush(const f16* lds, f16* __restrict__ g, int strideHalves, int tid) {
  __syncthreads();
#pragma unroll
  for (int q = 0; q < ROWS * 16 / THREADS; ++q) {
    const int idx = q * THREADS + tid, row = idx >> 4, c = idx & 15;
    *(half8*)(g + (size_t)row * strideHalves + c * 8) = *(const half8*)(lds + row * LDSH + c * 8);
  }
  __syncthreads();
}

// p in [0,136) -> (ti,tk), tk<=ti, ordered longest-K-first (ti-tk descending).
DEV void decode_pair(int p, int& ti, int& tk) {
  int t = (int)((sqrtf(8.f * p + 1.f) - 1.f) * 0.5f);
  while (t * (t + 1) / 2 > p) --t;
  while ((t + 1) * (t + 2) / 2 <= p) ++t;
  const int i2 = p - t * (t + 1) / 2;
  ti = (15 - t) + i2;
  tk = i2;
}

__global__ __launch_bounds__(256) void k_cast(const float* __restrict__ s, f16* __restrict__ d, int n4) {
  int i = blockIdx.x * 256 + threadIdx.x;
  if (i < n4) {
    float4 v = ((const float4*)s)[i];
    half4v h;
    h[0] = (f16)v.x; h[1] = (f16)v.y; h[2] = (f16)v.z; h[3] = (f16)v.w;
    ((half4v*)d)[i] = h;
  }
}

// qkvs = x @ w_qkv^T; per-head scatter. Each block's 128-wide f-window lies in ONE
// of the 6 qkv slots (t), so the epilogue branch is block-uniform.
__global__ __launch_bounds__(256) void k_qkv(const f16* __restrict__ xh, const f16* __restrict__ wh,
                                             f16* __restrict__ quh, f16* __restrict__ kuh,
                                             f16* __restrict__ vuh, f16* __restrict__ qch,
                                             f16* __restrict__ kch, f16* __restrict__ vcT) {
  __shared__ __align__(16) f16 lds[128 * LDSH];
  f16* As = lds; f16* Bs = lds + 128 * 64;
  const int tid = threadIdx.x, w = tid >> 6, l = tid & 63;
  const int tm = blockIdx.x * 128, tf = blockIdx.y * 128;
  const int wm = (w >> 1) * 64, wn = (w & 1) * 64;
  float4v acc[4][4] = {};
  for (int k0 = 0; k0 < DIM; k0 += 64) {
    stage64<128, 256>(xh + (size_t)tm * DIM + k0, DIM, As, tid);
    stage64<128, 256>(wh + (size_t)tf * DIM + k0, DIM, Bs, tid);
    __syncthreads();
    gemm64(As, Bs, wm, wn, l, acc);
    __syncthreads();
  }
  const int rbase = (l >> 4) * 4, cidx = l & 15;
  const int t = tf >> 10;
  const float sc = (t == 0 || t == 3) ? 0.125f : 1.f;
  if (t == 5) {  // vc transposed [h][d][n]: lane's 4 r-values are n-consecutive -> b64
#pragma unroll
    for (int mi = 0; mi < 4; ++mi)
#pragma unroll
      for (int ni = 0; ni < 4; ++ni) {
        const int f = tf + wn + ni * 16 + cidx;
        const int h = (f & 1023) >> 6, d = f & 63;
        half4v p;
#pragma unroll
        for (int r = 0; r < 4; ++r) p[r] = (f16)acc[mi][ni][r];
        *(half4v*)(vcT + ((size_t)h * DH + d) * N + (tm + wm + mi * 16 + rbase)) = p;
      }
  } else {
#pragma unroll
    for (int mi = 0; mi < 4; ++mi)
#pragma unroll
      for (int ni = 0; ni < 4; ++ni)
#pragma unroll
        for (int r = 0; r < 4; ++r)
          lds[(wm + mi * 16 + rbase + r) * LDSH + wn + ni * 16 + cidx] = (f16)(acc[mi][ni][r] * sc);
    __syncthreads();
    f16* dst = (t == 0) ? quh : (t == 1) ? kuh : (t == 2) ? vuh : (t == 3) ? qch : kch;
    const int hb = (tf & 1023) >> 6;
#pragma unroll
    for (int q = 0; q < 8; ++q) {
      const int idx = q * 256 + tid, row = idx >> 4, c = idx & 15;
      const int h = hb + (c >> 3), d0 = (c & 7) * 8, n = tm + row;
      *(half8*)(dst + ((size_t)h * N + n) * DH + d0) = *(const half8*)(lds + row * LDSH + c * 8);
    }
  }
}

// Per pair (a<=b): term1 tile (ti=b,tj=a) = tril(qc.vu^T) and sig tile (ti=a,tj=b)
// = triu1(sigmoid(qu.ku^T)). Uniform 2 GEMMs (K=64) per block, vectorized stores.
__global__ __launch_bounds__(256) void k_t1sig(const f16* __restrict__ qch, const f16* __restrict__ quh,
                                               const f16* __restrict__ vuh, const f16* __restrict__ kuh,
                                               f16* __restrict__ term1, f16* __restrict__ sigb, int h0) {
  __shared__ __align__(16) f16 lds[128 * LDSH];
  f16* As = lds; f16* Bs = lds + 128 * 64;
  int b, a;
  decode_pair(blockIdx.x, b, a);
  const int hl = blockIdx.y, h = h0 + hl;
  const int tid = threadIdx.x, w = tid >> 6, l = tid & 63;
  const int wm = (w >> 1) * 64, wn = (w & 1) * 64;
  const int rbase = (l >> 4) * 4, cidx = l & 15;
  const size_t ho = (size_t)h * N * DH;

  {  // term1
    float4v acc[4][4] = {};
    stage64<128, 256>(qch + ho + (size_t)(b * 128) * DH, DH, As, tid);
    stage64<128, 256>(vuh + ho + (size_t)(a * 128) * DH, DH, Bs, tid);
    __syncthreads();
    gemm64(As, Bs, wm, wn, l, acc);
    __syncthreads();
#pragma unroll
    for (int mi = 0; mi < 4; ++mi)
#pragma unroll
      for (int ni = 0; ni < 4; ++ni)
#pragma unroll
        for (int r = 0; r < 4; ++r) {
          const int i = b * 128 + wm + mi * 16 + rbase + r;
          const int j = a * 128 + wn + ni * 16 + cidx;
          lds[(wm + mi * 16 + rbase + r) * LDSH + wn + ni * 16 + cidx] = (j <= i) ? (f16)acc[mi][ni][r] : (f16)0.f;
        }
    flush<128, 256>(lds, term1 + (size_t)hl * N * N + (size_t)(b * 128) * N + a * 128, N, tid);
  }
  {  // sig
    float4v acc[4][4] = {};
    stage64<128, 256>(quh + ho + (size_t)(a * 128) * DH, DH, As, tid);
    stage64<128, 256>(kuh + ho + (size_t)(b * 128) * DH, DH, Bs, tid);
    __syncthreads();
    gemm64(As, Bs, wm, wn, l, acc);
    __syncthreads();
#pragma unroll
    for (int mi = 0; mi < 4; ++mi)
#pragma unroll
      for (int ni = 0; ni < 4; ++ni)
#pragma unroll
        for (int r = 0; r < 4; ++r) {
          const int i = a * 128 + wm + mi * 16 + rbase + r;
          const int j = b * 128 + wn + ni * 16 + cidx;
          const float x = acc[mi][ni][r];
          lds[(wm + mi * 16 + rbase + r) * LDSH + wn + ni * 16 + cidx] =
              (j > i) ? (f16)(1.f / (1.f + __expf(-x))) : (f16)0.f;
        }
    flush<128, 256>(lds, sigb + (size_t)hl * N * N + (size_t)(a * 128) * N + b * 128, N, tid);
  }
}

// scores = qc.kc^T - silu(term1 @ sig^T). 64x128 output tiles (pair>>1 + row-half),
// 128-thread blocks, longest-K first, silu fused via MFMA C-operand, f16 scores out.
// No triangular masking on the store: downstream kernels predicate on k<=i.
__global__ __launch_bounds__(128) void k_su(const f16* __restrict__ term1, const f16* __restrict__ sigb,
                                            const f16* __restrict__ qch, const f16* __restrict__ kch,
                                            f16* __restrict__ scob, int h0) {
  __shared__ __align__(16) f16 lds[64 * 64 + 128 * 64];  // As 8KB + Bs 16KB; epilogue overlays (64*LDSH <= total)
  f16* As = lds; f16* Bs = lds + 64 * 64;
  int ti, tk;
  decode_pair(blockIdx.x >> 1, ti, tk);
  const int half = blockIdx.x & 1;
  const int hl = blockIdx.y;
  const int tid = threadIdx.x, w = tid >> 6, l = tid & 63;
  const int wn = w * 64;
  const int r0 = ti * 128 + half * 64;
  float4v acc[4][4] = {};
  const f16* Ab = term1 + (size_t)hl * N * N + (size_t)r0 * N;
  const f16* Bb = sigb + (size_t)hl * N * N + (size_t)(tk * 128) * N;
  const int jhi = r0 + 64;
  for (int j0 = tk * 128; j0 < jhi; j0 += 64) {
    stage64<64, 128>(Ab + j0, N, As, tid);
    stage64<128, 128>(Bb + j0, N, Bs, tid);
    __syncthreads();
    gemm64(As, Bs, 0, wn, l, acc);
    __syncthreads();
  }
#pragma unroll
  for (int mi = 0; mi < 4; ++mi)
#pragma unroll
    for (int ni = 0; ni < 4; ++ni)
#pragma unroll
      for (int r = 0; r < 4; ++r) {
        const float x = acc[mi][ni][r];
        acc[mi][ni][r] = -(x / (1.f + __expf(-x)));  // -silu(Su)
      }
  const size_t ho = (size_t)(h0 + hl) * N * DH;
  stage64<64, 128>(qch + ho + (size_t)r0 * DH, DH, As, tid);
  stage64<128, 128>(kch + ho + (size_t)(tk * 128) * DH, DH, Bs, tid);
  __syncthreads();
  gemm64(As, Bs, 0, wn, l, acc);  // acc = Sc - silu(Su)
  __syncthreads();

  const int rbase = (l >> 4) * 4, cidx = l & 15;
#pragma unroll
  for (int mi = 0; mi < 4; ++mi)
#pragma unroll
    for (int ni = 0; ni < 4; ++ni)
#pragma unroll
      for (int r = 0; r < 4; ++r)
        lds[(mi * 16 + rbase + r) * LDSH + wn + ni * 16 + cidx] = (f16)acc[mi][ni][r];
  flush<64, 128>(lds, scob + (size_t)hl * N * N + (size_t)r0 * N + tk * 128, N, tid);
}

// Row softmax over k<=i on f16 scores; packed b128 f16 writes; zero-pads to the
// next 256 boundary so k_av's tile-granular K-loop reads no poison.
__global__ __launch_bounds__(256) void k_softmax(const f16* __restrict__ scob, f16* __restrict__ attn) {
  const int tid = threadIdx.x, l = tid & 63;
  const int row = blockIdx.x * 4 + (tid >> 6);
  const int hl = row >> 11, i = row & 2047;
  const f16* src = scob + (size_t)hl * N * N + (size_t)i * N;
  f16* dst = attn + (size_t)hl * N * N + (size_t)i * N;
  float v[32];
  float mx = -1e30f;
#pragma unroll
  for (int c = 0; c < 4; ++c) {
    const int idx = c * 64 + l;
    half8 h8 = ((const half8*)src)[idx];
#pragma unroll
    for (int e = 0; e < 8; ++e) {
      const int k = idx * 8 + e;
      const float val = (k <= i) ? (float)h8[e] : -1e30f;
      v[c * 8 + e] = val;
      mx = fmaxf(mx, val);
    }
  }
#pragma unroll
  for (int m = 1; m < 64; m <<= 1) mx = fmaxf(mx, __shfl_xor(mx, m, 64));
  float s = 0.f;
#pragma unroll
  for (int c = 0; c < 32; ++c) {
    const float ex = __expf(v[c] - mx);
    v[c] = ex;
    s += ex;
  }
#pragma unroll
  for (int m = 1; m < 64; m <<= 1) s += __shfl_xor(s, m, 64);
  const float inv = 1.f / s;
  const int kw8 = (((i >> 8) + 1) << 8) >> 3;
#pragma unroll
  for (int c = 0; c < 4; ++c) {
    const int idx = c * 64 + l;
    if (idx < kw8) {
      half8 o;
#pragma unroll
      for (int e = 0; e < 8; ++e) o[e] = (f16)(v[c * 8 + e] * inv);
      ((half8*)dst)[idx] = o;
    }
  }
}

// O[:, h*64:(h+1)*64] = attn @ vc; 64x64 tiles, longest-K-first, BK=64.
__global__ __launch_bounds__(256) void k_av(const f16* __restrict__ attn, const f16* __restrict__ vcT,
                                            f16* __restrict__ O, int h0) {
  __shared__ __align__(16) f16 As[64 * 64], Bs[64 * 64];
  const int mt = 31 - blockIdx.x, hl = blockIdx.y, h = h0 + hl;
  const int tid = threadIdx.x, w = tid >> 6, l = tid & 63;
  const int q = l >> 4, mm = l & 15;
  float4v acc[4] = {};
  const f16* Ab = attn + (size_t)hl * N * N + (size_t)(mt * 64) * N;
  const f16* Bb = vcT + (size_t)h * DH * N;
  const int jhi = (mt + 1) * 64;
  for (int j0 = 0; j0 < jhi; j0 += 64) {
    stage64<64, 256>(Ab + j0, N, As, tid);
    stage64<64, 256>(Bb + j0, N, Bs, tid);
    __syncthreads();
#pragma unroll
    for (int ks = 0; ks < 2; ++ks) {
      half8 bf = rdfrag(Bs, w * 16 + mm, ks, q);
#pragma unroll
      for (int mi = 0; mi < 4; ++mi) {
        half8 af = rdfrag(As, mm + mi * 16, ks, q);
        acc[mi] = __builtin_amdgcn_mfma_f32_16x16x32_f16(af, bf, acc[mi], 0, 0, 0);
      }
    }
    __syncthreads();
  }
  const int rbase = (l >> 4) * 4, cidx = l & 15;
#pragma unroll
  for (int mi = 0; mi < 4; ++mi)
#pragma unroll
    for (int r = 0; r < 4; ++r) {
      const int i = mt * 64 + mi * 16 + rbase + r;
      O[(size_t)i * (H * DH) + h * DH + w * 16 + cidx] = (f16)acc[mi][r];
    }
}

// out = O @ w_out^T, fp32 result.
__global__ __launch_bounds__(256) void k_out(const f16* __restrict__ Oh, const f16* __restrict__ wo,
                                             float* __restrict__ out) {
  __shared__ __align__(16) f16 lds[128 * LDSH];
  f16* As = lds; f16* Bs = lds + 128 * 64;
  const int tid = threadIdx.x, w = tid >> 6, l = tid & 63;
  const int tm = blockIdx.x * 128, tn = blockIdx.y * 128;
  const int wm = (w >> 1) * 64, wn = (w & 1) * 64;
  float4v acc[4][4] = {};
  for (int k0 = 0; k0 < DIM; k0 += 64) {
    stage64<128, 256>(Oh + (size_t)tm * DIM + k0, DIM, As, tid);
    stage64<128, 256>(wo + (size_t)tn * DIM + k0, DIM, Bs, tid);
    __syncthreads();
    gemm64(As, Bs, wm, wn, l, acc);
    __syncthreads();
  }
  const int rbase = (l >> 4) * 4, cidx = l & 15;
#pragma unroll
  for (int mi = 0; mi < 4; ++mi)
#pragma unroll
    for (int ni = 0; ni < 4; ++ni)
#pragma unroll
      for (int r = 0; r < 4; ++r) {
        const int n = tm + wm + mi * 16 + rbase + r;
        const int dmo = tn + wn + ni * 16 + cidx;
        out[(size_t)n * DIM + dmo] = acc[mi][ni][r];
      }
}

extern "C" void kernel_launch(void* const* d_in, const int* in_sizes, int n_in,
                              void* d_out, int out_size, void* d_ws, size_t ws_size,
                              hipStream_t stream) {
  const float* x = (const float*)d_in[0];
  const float* wqkv = (const float*)d_in[1];
  const float* wout = (const float*)d_in[2];
  float* out = (float*)d_out;
  char* ws = (char*)d_ws;

  size_t off = 0;
  auto alloc = [&](size_t b) { size_t o = off; off += (b + 255) & ~(size_t)255; return o; };
  f16* xh  = (f16*)(ws + alloc((size_t)N * DIM * 2));
  f16* wqh = (f16*)(ws + alloc((size_t)F6 * DIM * 2));
  f16* woh = (f16*)(ws + alloc((size_t)DIM * H * DH * 2));
  f16* quh = (f16*)(ws + alloc((size_t)H * N * DH * 2));
  f16* kuh = (f16*)(ws + alloc((size_t)H * N * DH * 2));
  f16* vuh = (f16*)(ws + alloc((size_t)H * N * DH * 2));
  f16* qch = (f16*)(ws + alloc((size_t)H * N * DH * 2));
  f16* kch = (f16*)(ws + alloc((size_t)H * N * DH * 2));
  f16* vcT = (f16*)(ws + alloc((size_t)H * DH * N * 2));
  f16* Oh  = (f16*)(ws + alloc((size_t)N * H * DH * 2));
  const size_t persist = off;

  // largest head-group G (any value 1..16): per-head footprint = term1+sig+scores, all f16
  const size_t per_head = (size_t)N * N * 2 * 3;
  int G = (ws_size > persist + 4096) ? (int)((ws_size - persist - 4096) / per_head) : 1;
  if (G < 1) G = 1;
  if (G > 16) G = 16;
  f16* term1 = (f16*)(ws + alloc((size_t)G * N * N * 2));   // reused as attn after softmax
  f16* sigb  = (f16*)(ws + alloc((size_t)G * N * N * 2));
  f16* scob  = (f16*)(ws + alloc((size_t)G * N * N * 2));

  k_cast<<<(N * DIM / 4 + 255) / 256, 256, 0, stream>>>(x, xh, N * DIM / 4);
  k_cast<<<(F6 * DIM / 4 + 255) / 256, 256, 0, stream>>>(wqkv, wqh, F6 * DIM / 4);
  k_cast<<<(DIM * H * DH / 4 + 255) / 256, 256, 0, stream>>>(wout, woh, DIM * H * DH / 4);

  k_qkv<<<dim3(N / 128, F6 / 128), 256, 0, stream>>>(xh, wqh, quh, kuh, vuh, qch, kch, vcT);

  for (int h0 = 0; h0 < H; h0 += G) {
    const int Gr = (H - h0 < G) ? (H - h0) : G;
    k_t1sig<<<dim3(136, Gr), 256, 0, stream>>>(qch, quh, vuh, kuh, term1, sigb, h0);
    k_su<<<dim3(272, Gr), 128, 0, stream>>>(term1, sigb, qch, kch, scob, h0);
    k_softmax<<<Gr * 512, 256, 0, stream>>>(scob, term1);
    k_av<<<dim3(32, Gr), 256, 0, stream>>>(term1, vcT, Oh, h0);
  }

  k_out<<<dim3(16, 8), 256, 0, stream>>>(Oh, woh, out);
}